// Round 5
// baseline (238.297 us; speedup 1.0000x reference)
//
#include <hip/hip_runtime.h>
#include <stdint.h>

#define LOG2E 1.4426950408889634f

typedef __bf16 v8bf __attribute__((ext_vector_type(8)));
typedef float v16f __attribute__((ext_vector_type(16)));

static constexpr int B = 4, N = 2048, FIN = 128, H = 4, DK = 32;
static constexpr int IT = N / 32;   // 64 i-tiles

__device__ __forceinline__ float exp2_fast(float x) {
#if __has_builtin(__builtin_amdgcn_exp2f)
  return __builtin_amdgcn_exp2f(x);
#else
  float r;
  asm("v_exp_f32 %0, %1" : "=v"(r) : "v"(x));
  return r;
#endif
}

__device__ __forceinline__ unsigned int bf16_rne(float f) {
  unsigned int u = __builtin_bit_cast(unsigned int, f);
  u += 0x7FFFu + ((u >> 16) & 1u);
  return u >> 16;
}

// ---------------- kernel 0: cast x->bf16 + wtb[h][d][f] bf16 ----------------
__global__ __launch_bounds__(256) void k_prep(const float* __restrict__ x,
                                              const float* __restrict__ W,
                                              unsigned short* __restrict__ xb,
                                              unsigned short* __restrict__ wtb) {
  int idx = blockIdx.x * 256 + threadIdx.x;
  constexpr int TX = B * N * FIN;          // 1048576
  if (idx < TX) {
    xb[idx] = (unsigned short)bf16_rne(x[idx]);
  } else {
    int j = idx - TX;                      // < H*DK*FIN = 16384
    int h = j >> 12, r = j & 4095, d = r >> 7, f = r & 127;
    wtb[j] = (unsigned short)bf16_rne(W[(h * FIN + f) * DK + d]);
  }
}

// ---------------- kernel 1: h projection via MFMA; h_t[bh][d][n] + el/er ----------------
__global__ __launch_bounds__(256) void k_hproj(const unsigned short* __restrict__ xb,
                                               const unsigned short* __restrict__ wtb,
                                               const float* __restrict__ a,
                                               unsigned short* __restrict__ h_t,
                                               float* __restrict__ el,
                                               float* __restrict__ er) {
  int blk = blockIdx.x;
  int b = blk >> 6, it = blk & 63;
  int tid = threadIdx.x;
  int head = tid >> 6, lane = tid & 63;
  int lrow = lane & 31, kh = lane >> 5;
  int bh = b * H + head;
  int n = it * 32 + lrow;
  const unsigned short* xp = xb + (b * N + n) * FIN + kh * 8;
  const unsigned short* wp = wtb + (head * DK + lrow) * FIN + kh * 8;
  v16f acc = {};
#pragma unroll
  for (int s = 0; s < FIN / 16; ++s) {
    v8bf av = __builtin_bit_cast(v8bf, *(const int4*)(wp + s * 16));
    v8bf bv = __builtin_bit_cast(v8bf, *(const int4*)(xp + s * 16));
    acc = __builtin_amdgcn_mfma_f32_32x32x16_bf16(av, bv, acc, 0, 0, 0);
  }
  float pel = 0.f, per = 0.f;
#pragma unroll
  for (int r = 0; r < 16; ++r) {
    int d = (r & 3) + 8 * (r >> 2) + 4 * kh;   // C/D row mapping (32x32 bf16)
    float hv = acc[r];
    h_t[(bh * DK + d) * N + n] = (unsigned short)bf16_rne(hv);
    pel = fmaf(hv, a[head * 2 * DK + d], pel);
    per = fmaf(hv, a[head * 2 * DK + DK + d], per);
  }
  pel += __shfl_xor(pel, 32);
  per += __shfl_xor(per, 32);
  if (kh == 0) {
    el[bh * N + n] = pel * LOG2E;
    er[bh * N + n] = per * LOG2E;
  }
}

// ---------------- kernel 2: fused attention, raw adj streaming, final out ----------------
// block = (b, it): 512 threads = 8 waves = (head 0..3) x (jq 0..1, 1024 j each)
__global__ __launch_bounds__(512, 6) void k_attn(const int* __restrict__ adj,
                                                 const unsigned short* __restrict__ h_t,
                                                 const float* __restrict__ el,
                                                 const float* __restrict__ er,
                                                 float* __restrict__ out) {
  __shared__ float ersh[H * N];     // 32 KB: er for all heads of this b
  __shared__ float part[H * 1024];  // 16 KB: [head][i*32+d]
  __shared__ float lsh[H * 32];     // [head][i]
  int blk = blockIdx.x;
  int b = blk >> 6, it = blk & 63;
  int tid = threadIdx.x;
  int wave = tid >> 6;
  int head = wave & 3, jq = wave >> 2;
  int lane = tid & 63, lrow = lane & 31, kh = lane >> 5;
  int ig = it * 32 + lrow, bh = b * H + head;

  // cooperative er load: 8192 floats, coalesced float4
  {
    const float4* esrc = (const float4*)(er + b * H * N);
    float4* edst = (float4*)ersh;
#pragma unroll
    for (int r = 0; r < 4; ++r) edst[tid + r * 512] = esrc[tid + r * 512];
  }
  __syncthreads();

  float eli = el[bh * N + ig];
  int j0 = jq * 1024 + kh * 8;
  const int* arow = adj + (size_t)(b * N + ig) * N + j0;
  const unsigned short* hp = h_t + (size_t)(bh * DK + lrow) * N + j0;
  const float* ep = ersh + head * N + j0;

  v16f acc = {};
  float lsum = 0.f;

  // depth-2 software pipeline: slot0 = even steps, slot1 = odd steps
  int4 A0a = *(const int4*)(arow);
  int4 A0b = *(const int4*)(arow + 4);
  int4 H0 = *(const int4*)(hp);
  int4 A1a = *(const int4*)(arow + 16);
  int4 A1b = *(const int4*)(arow + 20);
  int4 H1 = *(const int4*)(hp + 16);

  auto step = [&](int4 aa, int4 ab, int4 hb, int s) {
    float4 ea = *(const float4*)(ep + s * 16);
    float4 eb = *(const float4*)(ep + s * 16 + 4);
    int ad[8] = {aa.x, aa.y, aa.z, aa.w, ab.x, ab.y, ab.z, ab.w};
    float ev[8] = {ea.x, ea.y, ea.z, ea.w, eb.x, eb.y, eb.z, eb.w};
    unsigned ub[8];
#pragma unroll
    for (int k = 0; k < 8; ++k) {
      float tt = eli + ev[k];
      tt = fmaxf(tt, 0.2f * tt);            // leaky relu (log2e pre-folded)
      float pv = exp2_fast(tt);
      unsigned u = __builtin_bit_cast(unsigned, pv) & 0xFFFF0000u;
      u = ad[k] ? u : 0u;                   // adjacency mask
      ub[k] = u;
      lsum += __builtin_bit_cast(float, u); // truncated: num/den consistent
    }
    unsigned u0 = __builtin_amdgcn_perm(ub[1], ub[0], 0x07060302u);
    unsigned u1 = __builtin_amdgcn_perm(ub[3], ub[2], 0x07060302u);
    unsigned u2 = __builtin_amdgcn_perm(ub[5], ub[4], 0x07060302u);
    unsigned u3 = __builtin_amdgcn_perm(ub[7], ub[6], 0x07060302u);
    uint4 au = {u0, u1, u2, u3};
    acc = __builtin_amdgcn_mfma_f32_32x32x16_bf16(
        __builtin_bit_cast(v8bf, au), __builtin_bit_cast(v8bf, hb), acc, 0, 0, 0);
  };

#pragma unroll 4
  for (int s = 0; s < 64; s += 2) {
    int4 aa = A0a, ab = A0b, hb = H0;
    if (s + 2 < 64) {
      int o = (s + 2) * 16;
      A0a = *(const int4*)(arow + o);
      A0b = *(const int4*)(arow + o + 4);
      H0 = *(const int4*)(hp + o);
    }
    step(aa, ab, hb, s);
    aa = A1a; ab = A1b; hb = H1;
    if (s + 3 < 64) {
      int o = (s + 3) * 16;
      A1a = *(const int4*)(arow + o);
      A1b = *(const int4*)(arow + o + 4);
      H1 = *(const int4*)(hp + o);
    }
    step(aa, ab, hb, s + 1);
  }

  lsum += __shfl_xor(lsum, 32);   // combine kh halves: full jq-range row sum

  // staged (non-atomic) cross-jq reduction: jq0 writes, jq1 accumulates
  if (jq == 0) {
    if (lane < 32) lsh[head * 32 + lane] = lsum;
#pragma unroll
    for (int r = 0; r < 16; ++r) {
      int rowl = (r & 3) + 8 * (r >> 2) + 4 * kh;
      part[head * 1024 + rowl * 32 + lrow] = acc[r];
    }
  }
  __syncthreads();
  if (jq == 1) {
    if (lane < 32) lsh[head * 32 + lane] += lsum;
#pragma unroll
    for (int r = 0; r < 16; ++r) {
      int rowl = (r & 3) + 8 * (r >> 2) + 4 * kh;
      part[head * 1024 + rowl * 32 + lrow] += acc[r];
    }
  }
  __syncthreads();

  // 4096 outputs / 512 threads = two float4 each, coalesced
  int e = tid * 8;
  int rh = e >> 10;
  int ri = (e >> 5) & 31;
  int rd = e & 31;
  float inv = 1.0f / lsh[rh * 32 + ri];
  float4 s0 = *(const float4*)&part[rh * 1024 + ri * 32 + rd];
  float4 s1 = *(const float4*)&part[rh * 1024 + ri * 32 + rd + 4];
  float4 o0 = {s0.x * inv, s0.y * inv, s0.z * inv, s0.w * inv};
  float4 o1 = {s1.x * inv, s1.y * inv, s1.z * inv, s1.w * inv};
  float* op = out + (size_t)((b * H + rh) * N + it * 32 + ri) * DK + rd;
  *(float4*)op = o0;
  *(float4*)(op + 4) = o1;
}

extern "C" void kernel_launch(void* const* d_in, const int* in_sizes, int n_in,
                              void* d_out, int out_size, void* d_ws, size_t ws_size,
                              hipStream_t stream) {
  const float* x = (const float*)d_in[0];
  const int* adj = (const int*)d_in[1];
  const float* W = (const float*)d_in[2];
  const float* a = (const float*)d_in[3];
  float* out = (float*)d_out;
  char* ws = (char*)d_ws;

  unsigned short* h_t = (unsigned short*)(ws);             // 2 MB  [B][H][DK][N]
  float* el = (float*)(ws + 0x200000);                     // 128 KB
  float* er = (float*)(ws + 0x220000);                     // 128 KB
  unsigned short* wtb = (unsigned short*)(ws + 0x240000);  // 32 KB
  unsigned short* xb = (unsigned short*)(ws + 0x250000);   // 2 MB

  hipLaunchKernelGGL(k_prep, dim3((B * N * FIN + H * DK * FIN) / 256), dim3(256), 0, stream,
                     x, W, xb, wtb);
  hipLaunchKernelGGL(k_hproj, dim3(B * IT), dim3(256), 0, stream, xb, wtb, a, h_t, el, er);
  hipLaunchKernelGGL(k_attn, dim3(B * IT), dim3(512), 0, stream, adj, h_t, el, er, out);
}

// Round 6
// 163.114 us; speedup vs baseline: 1.4609x; 1.4609x over previous
//
#include <hip/hip_runtime.h>
#include <stdint.h>

#define LOG2E 1.4426950408889634f

typedef __bf16 v8bf __attribute__((ext_vector_type(8)));
typedef float v16f __attribute__((ext_vector_type(16)));

static constexpr int B = 4, N = 2048, FIN = 128, H = 4, DK = 32;
static constexpr int IT = N / 32;   // 64 i-tiles

__device__ __forceinline__ float exp2_fast(float x) {
#if __has_builtin(__builtin_amdgcn_exp2f)
  return __builtin_amdgcn_exp2f(x);
#else
  float r;
  asm("v_exp_f32 %0, %1" : "=v"(r) : "v"(x));
  return r;
#endif
}

__device__ __forceinline__ unsigned int bf16_rne(float f) {
  unsigned int u = __builtin_bit_cast(unsigned int, f);
  u += 0x7FFFu + ((u >> 16) & 1u);
  return u >> 16;
}

// pack 8 floats -> v8bf (RNE)
__device__ __forceinline__ v8bf pack8(const float* v) {
  uint4 u;
  u.x = bf16_rne(v[0]) | (bf16_rne(v[1]) << 16);
  u.y = bf16_rne(v[2]) | (bf16_rne(v[3]) << 16);
  u.z = bf16_rne(v[4]) | (bf16_rne(v[5]) << 16);
  u.w = bf16_rne(v[6]) | (bf16_rne(v[7]) << 16);
  return __builtin_bit_cast(v8bf, u);
}

// ---------------- kernel 1: h projection via MFMA (f32 in, casts fused) ----------------
// block = (b, it), 256 threads = 4 waves (one per head).
// A = W[head][f][d] (lane d coalesced), B = x[b][n][f]; D tile rows=d, cols=n.
__global__ __launch_bounds__(256) void k_hproj(const float* __restrict__ x,
                                               const float* __restrict__ W,
                                               const float* __restrict__ a,
                                               unsigned short* __restrict__ h_t,
                                               float* __restrict__ el,
                                               float* __restrict__ er) {
  int blk = blockIdx.x;
  int b = blk >> 6, it = blk & 63;
  int tid = threadIdx.x;
  int head = tid >> 6, lane = tid & 63;
  int lrow = lane & 31, kh = lane >> 5;
  int bh = b * H + head;
  int n = it * 32 + lrow;
  const float* xp = x + (b * N + n) * FIN + kh * 8;   // 8 f's per MFMA step
  const float* wp = W + head * FIN * DK + lrow;       // + f*DK
  v16f acc = {};
#pragma unroll
  for (int s = 0; s < FIN / 16; ++s) {
    float xv[8], wv[8];
    *(float4*)&xv[0] = *(const float4*)(xp + s * 16);
    *(float4*)&xv[4] = *(const float4*)(xp + s * 16 + 4);
    int fb = s * 16 + kh * 8;
#pragma unroll
    for (int k = 0; k < 8; ++k) wv[k] = wp[(fb + k) * DK];
    acc = __builtin_amdgcn_mfma_f32_32x32x16_bf16(pack8(wv), pack8(xv), acc, 0, 0, 0);
  }
  float pel = 0.f, per = 0.f;
#pragma unroll
  for (int r = 0; r < 16; ++r) {
    int d = (r & 3) + 8 * (r >> 2) + 4 * kh;   // C/D row mapping (32x32 bf16)
    float hv = acc[r];
    h_t[(bh * DK + d) * N + n] = (unsigned short)bf16_rne(hv);
    pel = fmaf(hv, a[head * 2 * DK + d], pel);
    per = fmaf(hv, a[head * 2 * DK + DK + d], per);
  }
  pel += __shfl_xor(pel, 32);
  per += __shfl_xor(per, 32);
  if (kh == 0) {
    el[bh * N + n] = pel * LOG2E;
    er[bh * N + n] = per * LOG2E;
  }
}

// ---------------- kernel 2: fused attention (raw adj), dual-stream, final out ----------
// block = (b, it): 1024 threads = 16 waves = (head 0..3) x (jq 0..3, 512 j each).
// Each wave runs TWO independent 256-j streams for 2x memory-level parallelism.
__global__ __launch_bounds__(1024, 4) void k_attn(const int* __restrict__ adj,
                                                  const unsigned short* __restrict__ h_t,
                                                  const float* __restrict__ el,
                                                  const float* __restrict__ er,
                                                  float* __restrict__ out) {
  __shared__ float ersh[H * N];     // 32 KB: er for all heads of this b
  __shared__ float part[H * 1024];  // 16 KB: [head][i*32+d]
  __shared__ float lsh[H * 32];     // [head][i]
  int blk = blockIdx.x;
  int b = blk >> 6, it = blk & 63;
  int tid = threadIdx.x;
  int wave = tid >> 6;
  int head = wave & 3, jq = wave >> 2;
  int lane = tid & 63, lrow = lane & 31, kh = lane >> 5;
  int ig = it * 32 + lrow, bh = b * H + head;

  {  // cooperative er load: 8192 floats = 2048 float4
    const float4* es = (const float4*)(er + b * H * N);
    float4* ed = (float4*)ersh;
    ed[tid] = es[tid];
    ed[tid + 1024] = es[tid + 1024];
  }
  part[tid] = 0.f;
  part[tid + 1024] = 0.f;
  part[tid + 2048] = 0.f;
  part[tid + 3072] = 0.f;
  if (tid < H * 32) lsh[tid] = 0.f;
  __syncthreads();

  float eli = el[bh * N + ig];
  int j0 = jq * 512 + kh * 8;
  const int* arow = adj + (size_t)(b * N + ig) * N + j0;
  const unsigned short* hp = h_t + (size_t)(bh * DK + lrow) * N + j0;
  const float* ep = ersh + head * N + j0;

  v16f acc0 = {}, acc1 = {};
  float ls0 = 0.f, ls1 = 0.f;

  // depth-1 prefetch per stream; stream1 covers +256 j
  int4 A0a = *(const int4*)(arow);
  int4 A0b = *(const int4*)(arow + 4);
  int4 H0 = *(const int4*)(hp);
  int4 A1a = *(const int4*)(arow + 256);
  int4 A1b = *(const int4*)(arow + 260);
  int4 H1 = *(const int4*)(hp + 256);

  auto step = [&](int4 aa, int4 ab, int4 hb, int eoff, v16f& acc, float& lsum) {
    float4 ea = *(const float4*)(ep + eoff);
    float4 eb = *(const float4*)(ep + eoff + 4);
    int ad[8] = {aa.x, aa.y, aa.z, aa.w, ab.x, ab.y, ab.z, ab.w};
    float ev[8] = {ea.x, ea.y, ea.z, ea.w, eb.x, eb.y, eb.z, eb.w};
    unsigned ub[8];
#pragma unroll
    for (int k = 0; k < 8; ++k) {
      float tt = eli + ev[k];
      tt = fmaxf(tt, 0.2f * tt);            // leaky relu (log2e pre-folded)
      float pv = exp2_fast(tt);
      unsigned u = __builtin_bit_cast(unsigned, pv) & 0xFFFF0000u;
      u = ad[k] ? u : 0u;                   // adjacency mask
      ub[k] = u;
      lsum += __builtin_bit_cast(float, u); // truncated: num/den consistent
    }
    unsigned u0 = __builtin_amdgcn_perm(ub[1], ub[0], 0x07060302u);
    unsigned u1 = __builtin_amdgcn_perm(ub[3], ub[2], 0x07060302u);
    unsigned u2 = __builtin_amdgcn_perm(ub[5], ub[4], 0x07060302u);
    unsigned u3 = __builtin_amdgcn_perm(ub[7], ub[6], 0x07060302u);
    uint4 au = {u0, u1, u2, u3};
    acc = __builtin_amdgcn_mfma_f32_32x32x16_bf16(
        __builtin_bit_cast(v8bf, au), __builtin_bit_cast(v8bf, hb), acc, 0, 0, 0);
  };

  for (int s = 0; s < 16; ++s) {
    int4 aa = A0a, ab = A0b, hb = H0;
    if (s + 1 < 16) {
      int o = (s + 1) * 16;
      A0a = *(const int4*)(arow + o);
      A0b = *(const int4*)(arow + o + 4);
      H0 = *(const int4*)(hp + o);
    }
    step(aa, ab, hb, s * 16, acc0, ls0);
    aa = A1a; ab = A1b; hb = H1;
    if (s + 1 < 16) {
      int o = 256 + (s + 1) * 16;
      A1a = *(const int4*)(arow + o);
      A1b = *(const int4*)(arow + o + 4);
      H1 = *(const int4*)(hp + o);
    }
    step(aa, ab, hb, 256 + s * 16, acc1, ls1);
  }

  float lsum = ls0 + ls1;
  lsum += __shfl_xor(lsum, 32);   // combine kh halves: full 512-j row sum
  if (lane < 32) atomicAdd(&lsh[head * 32 + lane], lsum);
#pragma unroll
  for (int r = 0; r < 16; ++r) {
    int rowl = (r & 3) + 8 * (r >> 2) + 4 * kh;   // i-row within tile
    atomicAdd(&part[head * 1024 + rowl * 32 + lrow], acc0[r] + acc1[r]);
  }
  __syncthreads();

  // 4096 outputs / 1024 threads = one float4 each, coalesced
  int e = tid * 4;
  int rh = e >> 10;
  int ri = (e >> 5) & 31;
  int rd = e & 31;
  float inv = 1.0f / lsh[rh * 32 + ri];
  float4 s4 = *(const float4*)&part[rh * 1024 + ri * 32 + rd];
  float4 o = {s4.x * inv, s4.y * inv, s4.z * inv, s4.w * inv};
  *(float4*)&out[(size_t)((b * H + rh) * N + it * 32 + ri) * DK + rd] = o;
}

extern "C" void kernel_launch(void* const* d_in, const int* in_sizes, int n_in,
                              void* d_out, int out_size, void* d_ws, size_t ws_size,
                              hipStream_t stream) {
  const float* x = (const float*)d_in[0];
  const int* adj = (const int*)d_in[1];
  const float* W = (const float*)d_in[2];
  const float* a = (const float*)d_in[3];
  float* out = (float*)d_out;
  char* ws = (char*)d_ws;

  unsigned short* h_t = (unsigned short*)(ws);   // 2 MB  [B][H][DK][N]
  float* el = (float*)(ws + 0x200000);           // 128 KB
  float* er = (float*)(ws + 0x220000);           // 128 KB

  hipLaunchKernelGGL(k_hproj, dim3(B * IT), dim3(256), 0, stream, x, W, a, h_t, el, er);
  hipLaunchKernelGGL(k_attn, dim3(B * IT), dim3(1024), 0, stream, adj, h_t, el, er, out);
}